// Round 5
// baseline (100.802 us; speedup 1.0000x reference)
//
#include <hip/hip_runtime.h>

#define BDIM 128
#define TDIM 512
#define DDIM 64
#define HDIM 256
#define WT 64                          // timesteps per wave
#define TBLK 256                       // timesteps per block (4 waves)
#define NTG (TDIM / WT)                // 8 partial planes
#define HH_FLOATS (BDIM * 4 * HDIM)    // 131072 floats = 512 KB

typedef short s16x8 __attribute__((ext_vector_type(8)));
typedef float f32x4 __attribute__((ext_vector_type(4)));

__device__ __forceinline__ short f2bf(float f) {
  __bf16 b = (__bf16)f;
  return __builtin_bit_cast(short, b);
}

__device__ __forceinline__ s16x8 pack_bf8(float4 lo, float4 hi) {
  s16x8 v;
  v[0] = f2bf(lo.x); v[1] = f2bf(lo.y); v[2] = f2bf(lo.z); v[3] = f2bf(lo.w);
  v[4] = f2bf(hi.x); v[5] = f2bf(hi.y); v[6] = f2bf(hi.z); v[7] = f2bf(hi.w);
  return v;
}

__device__ __forceinline__ float rcpf(float x) { return __builtin_amdgcn_rcpf(x); }
__device__ __forceinline__ float sigm(float x) { return rcpf(1.0f + __expf(-x)); }
__device__ __forceinline__ float tanh_fast(float x) { return 1.0f - 2.0f * rcpf(__expf(2.0f * x) + 1.0f); }

// hh[b][colw] = Whh[colw]·h0[b] + bih[colw] + bhh[colw]
__global__ __launch_bounds__(256) void hh_kernel(
    const float* __restrict__ h0, const float* __restrict__ Whh,
    const float* __restrict__ bih, const float* __restrict__ bhh,
    float* __restrict__ hh)
{
  const int b = blockIdx.x, c = blockIdx.y, tid = threadIdx.x;
  __shared__ float hs[HDIM];
  hs[tid] = h0[b * HDIM + tid];
  __syncthreads();

  const int colw = c * 256 + tid;
  const float4* wr = (const float4*)(Whh + (size_t)colw * HDIM);
  const float4* hv = (const float4*)hs;
  float acc = 0.f;
  #pragma unroll 8
  for (int k = 0; k < HDIM / 4; ++k) {
    float4 w = wr[k], h4 = hv[k];
    acc += w.x * h4.x + w.y * h4.y + w.z * h4.z + w.w * h4.w;
  }
  hh[(size_t)b * 1024 + colw] = acc + bih[colw] + bhh[colw];
}

// Grid: (128, 16, 2), 256 threads (4 waves). Block = (b, 16-col h-chunk, t-half).
// Waves split the 256-t block range: wave w owns t in [z*256 + w*64, +64).
// All A-fragments for the wave's 4 K-iterations are preloaded to registers:
// the inner loop is pure compute (MFMA + LDS broadcast + cell math), no vmcnt.
__global__ __launch_bounds__(256, 4) void fused_lstm(
    const float* __restrict__ x, const float* __restrict__ c0,
    const float* __restrict__ Wih, const float* __restrict__ hh,
    const int* __restrict__ longp, float* __restrict__ sbuf)
{
  const int b    = blockIdx.x;
  const int hc   = blockIdx.y;          // 0..15 (16 h-cols each)
  const int z    = blockIdx.z;          // 0..1  (t-half)
  const int tid  = threadIdx.x;
  const int wave = tid >> 6;            // 0..3 (t-slice within block)
  const int lane = tid & 63;
  const int col  = lane & 15;
  const int kg   = lane >> 4;           // 0..3
  const int h    = hc * 16 + col;

  __shared__ float w0s[TBLK];
  __shared__ float w1s[TBLK];

  const float* xb = x + (size_t)b * (TDIM * DDIM);
  const float inv_long = 1.0f / (float)(*longp);

  {
    const int tt = z * TBLK + tid;
    w0s[tid] = (tt == 0) ? 0.f : xb[tt * DDIM + 0] * inv_long;  // t=0 mask
    w1s[tid] = (tt == 0) ? 0.f : xb[tt * DDIM + 1];
  }
  __syncthreads();

  float hhv[4];
  #pragma unroll
  for (int g = 0; g < 4; ++g) hhv[g] = hh[(size_t)b * 1024 + g * HDIM + h];
  const float cprev = c0[b * HDIM + h];

  // W_ih fragments (shared h-range across waves; L2-cached redundancy)
  s16x8 wf[4][2];
  #pragma unroll
  for (int g = 0; g < 4; ++g) {
    const float4* wrow = (const float4*)(Wih + (size_t)(g * HDIM + h) * DDIM);
    #pragma unroll
    for (int ks = 0; ks < 2; ++ks)
      wf[g][ks] = pack_bf8(wrow[kg * 2 + ks * 8], wrow[kg * 2 + ks * 8 + 1]);
  }

  // Preload ALL A-fragments for this wave's 64 timesteps (4 tiles of 16):
  // row = t0 + tb + col, k = kg*8 + j (+32). 32 VGPRs packed bf16.
  const int t0 = z * TBLK + wave * WT;
  const float* arow = xb + (size_t)(t0 + col) * DDIM + kg * 8;
  s16x8 a0r[4], a1r[4];
  #pragma unroll
  for (int it = 0; it < 4; ++it) {
    const float* p = arow + (size_t)(it * 16) * DDIM;
    float4 q0 = *(const float4*)(p + 0);
    float4 q1 = *(const float4*)(p + 4);
    float4 q2 = *(const float4*)(p + 32);
    float4 q3 = *(const float4*)(p + 36);
    a0r[it] = pack_bf8(q0, q1);
    a1r[it] = pack_bf8(q2, q3);
  }

  float s0h = 0.f, s1h = 0.f, s0c = 0.f, s1c = 0.f;

  #pragma unroll
  for (int it = 0; it < 4; ++it) {
    f32x4 acc[4];
    #pragma unroll
    for (int g = 0; g < 4; ++g) {
      f32x4 zc = {hhv[g], hhv[g], hhv[g], hhv[g]};  // bias+hh folded into C
      zc = __builtin_amdgcn_mfma_f32_16x16x32_bf16(a0r[it], wf[g][0], zc, 0, 0, 0);
      zc = __builtin_amdgcn_mfma_f32_16x16x32_bf16(a1r[it], wf[g][1], zc, 0, 0, 0);
      acc[g] = zc;
    }

    #pragma unroll
    for (int r = 0; r < 4; ++r) {
      const int lt = wave * WT + it * 16 + kg * 4 + r;  // C/D row = kg*4+r
      float ig = sigm(acc[0][r]);
      float fg = sigm(acc[1][r]);
      float gg = tanh_fast(acc[2][r]);
      float og = sigm(acc[3][r]);
      float cc = fg * cprev + ig * gg;
      float hv = og * tanh_fast(cc);
      float a0w = w0s[lt], a1w = w1s[lt];  // w*[t=0]==0 handles the mask
      s0h += hv * a0w; s1h += hv * a1w;
      s0c += cc * a0w; s1c += cc * a1w;
    }
  }

  // reduce over the 4 k-groups (lanes sharing col)
  s0h += __shfl_xor(s0h, 16, 64); s0h += __shfl_xor(s0h, 32, 64);
  s1h += __shfl_xor(s1h, 16, 64); s1h += __shfl_xor(s1h, 32, 64);
  s0c += __shfl_xor(s0c, 16, 64); s0c += __shfl_xor(s0c, 32, 64);
  s1c += __shfl_xor(s1c, 16, 64); s1c += __shfl_xor(s1c, 32, 64);

  if (kg == 0) {
    float* P = sbuf + HH_FLOATS;
    const int tg = z * 4 + wave;                 // 0..7 partial plane
    const size_t idx = (size_t)b * HDIM + h;
    P[((size_t)(tg * 4 + 0) * BDIM * HDIM) + idx] = s0h;
    P[((size_t)(tg * 4 + 1) * BDIM * HDIM) + idx] = s1h;
    P[((size_t)(tg * 4 + 2) * BDIM * HDIM) + idx] = s0c;
    P[((size_t)(tg * 4 + 3) * BDIM * HDIM) + idx] = s1c;
  }
}

// Grid: 128 blocks (b), 256 threads. Sums tg partials + GEMV epilogue.
__global__ __launch_bounds__(256) void out_kernel(
    const float* __restrict__ x, const float* __restrict__ f1w,
    const float* __restrict__ f1b, const float* __restrict__ f2w,
    const float* __restrict__ f2b, const int* __restrict__ longp,
    const float* __restrict__ sbuf, float* __restrict__ out)
{
  const int b = blockIdx.x, tid = threadIdx.x;
  __shared__ float s0h[256], s1h[256], s0c[256], s1c[256];
  __shared__ float wsum[8];
  const float* xb = x + (size_t)b * (TDIM * DDIM);
  const float* P  = sbuf + HH_FLOATS;
  const size_t idx = (size_t)b * HDIM + tid;

  float v0 = 0.f, v1 = 0.f, v2 = 0.f, v3 = 0.f;
  #pragma unroll
  for (int tg = 0; tg < NTG; ++tg) {
    v0 += P[((size_t)(tg * 4 + 0) * BDIM * HDIM) + idx];
    v1 += P[((size_t)(tg * 4 + 1) * BDIM * HDIM) + idx];
    v2 += P[((size_t)(tg * 4 + 2) * BDIM * HDIM) + idx];
    v3 += P[((size_t)(tg * 4 + 3) * BDIM * HDIM) + idx];
  }
  s0h[tid] = v0; s1h[tid] = v1; s0c[tid] = v2; s1c[tid] = v3;

  float w0p = 0.f, w1p = 0.f;
  for (int t = tid; t < TDIM; t += 256) {
    w0p += xb[t * DDIM];
    w1p += xb[t * DDIM + 1];
  }
  #pragma unroll
  for (int off = 1; off < 64; off <<= 1) {
    w0p += __shfl_xor(w0p, off, 64);
    w1p += __shfl_xor(w1p, off, 64);
  }
  if ((tid & 63) == 0) { wsum[tid >> 6] = w0p; wsum[4 + (tid >> 6)] = w1p; }
  __syncthreads();

  const float inv_long = 1.0f / (float)(*longp);
  const float W0 = (wsum[0] + wsum[1] + wsum[2] + wsum[3]) * inv_long; // all t
  const float W1 = (wsum[4] + wsum[5] + wsum[6] + wsum[7]);

  float rh, rc;
  if (tid < 128) {                       // "first": f1_w with w0-weighted sums
    const float4* wr = (const float4*)(f1w + (size_t)tid * HDIM);
    float ah = 0.f, ac = 0.f;
    #pragma unroll 8
    for (int k = 0; k < HDIM / 4; ++k) {
      float4 w = wr[k];
      ah += w.x * s0h[4*k] + w.y * s0h[4*k+1] + w.z * s0h[4*k+2] + w.w * s0h[4*k+3];
      ac += w.x * s0c[4*k] + w.y * s0c[4*k+1] + w.z * s0c[4*k+2] + w.w * s0c[4*k+3];
    }
    const float bb = f1b[tid];
    rh = ah + bb * W0;
    rc = ac + bb * W0;
  } else {                               // "second": f2_w with w1-weighted sums
    const int k0 = tid - 128;
    const float4* wr = (const float4*)(f2w + (size_t)k0 * HDIM);
    float ah = 0.f, ac = 0.f;
    #pragma unroll 8
    for (int k = 0; k < HDIM / 4; ++k) {
      float4 w = wr[k];
      ah += w.x * s1h[4*k] + w.y * s1h[4*k+1] + w.z * s1h[4*k+2] + w.w * s1h[4*k+3];
      ac += w.x * s1c[4*k] + w.y * s1c[4*k+1] + w.z * s1c[4*k+2] + w.w * s1c[4*k+3];
    }
    const float bb = f2b[k0];
    rh = ah + bb * W1;
    rc = ac + bb * W1;
  }
  out[b * HDIM + tid] = rh;                      // agg(h_all) -> (1,B,256)
  out[BDIM * HDIM + b * HDIM + tid] = rc;        // agg(c_all)
}

extern "C" void kernel_launch(void* const* d_in, const int* in_sizes, int n_in,
                              void* d_out, int out_size, void* d_ws, size_t ws_size,
                              hipStream_t stream) {
  const float* x   = (const float*)d_in[0];
  const float* h0  = (const float*)d_in[1];
  const float* c0  = (const float*)d_in[2];
  const float* Wih = (const float*)d_in[3];
  const float* Whh = (const float*)d_in[4];
  const float* bih = (const float*)d_in[5];
  const float* bhh = (const float*)d_in[6];
  const float* f1w = (const float*)d_in[7];
  const float* f1b = (const float*)d_in[8];
  const float* f2w = (const float*)d_in[9];
  const float* f2b = (const float*)d_in[10];
  const int*  longp = (const int*)d_in[11];
  float* out  = (float*)d_out;
  float* sbuf = (float*)d_ws;   // hh (512 KB) + partials (4 MB) = 4.5 MB

  dim3 gh(BDIM, 4);
  hh_kernel<<<gh, 256, 0, stream>>>(h0, Whh, bih, bhh, sbuf);
  dim3 g1(BDIM, 16, 2);
  fused_lstm<<<g1, 256, 0, stream>>>(x, c0, Wih, sbuf, longp, sbuf);
  out_kernel<<<BDIM, 256, 0, stream>>>(x, f1w, f1b, f2w, f2b, longp, sbuf, out);
}

// Round 6
// 76.249 us; speedup vs baseline: 1.3220x; 1.3220x over previous
//
#include <hip/hip_runtime.h>

#define BDIM 128
#define TDIM 512
#define DDIM 64
#define HDIM 256
#define CH   32                        // timesteps per staged LDS chunk
#define ZT   256                       // timesteps per block (blockIdx.z half)
#define NCH  (ZT / CH)                 // 8 chunks
#define LDR  68                        // padded LDS row stride in dwords (64+4)
#define NPL  4                         // partial planes: z*2 + th

typedef short s16x8 __attribute__((ext_vector_type(8)));
typedef float f32x4 __attribute__((ext_vector_type(4)));

__device__ __forceinline__ short f2bf(float f) {
  __bf16 b = (__bf16)f;
  return __builtin_bit_cast(short, b);
}

__device__ __forceinline__ s16x8 pack_bf8(float4 lo, float4 hi) {
  s16x8 v;
  v[0] = f2bf(lo.x); v[1] = f2bf(lo.y); v[2] = f2bf(lo.z); v[3] = f2bf(lo.w);
  v[4] = f2bf(hi.x); v[5] = f2bf(hi.y); v[6] = f2bf(hi.z); v[7] = f2bf(hi.w);
  return v;
}

__device__ __forceinline__ float rcpf(float x) { return __builtin_amdgcn_rcpf(x); }
__device__ __forceinline__ float sigm(float x) { return rcpf(1.0f + __expf(-x)); }
__device__ __forceinline__ float tanh_fast(float x) { return 1.0f - 2.0f * rcpf(__expf(2.0f * x) + 1.0f); }

// Grid: (128, 4, 2), 512 threads = 8 waves. Block = (b, 64-h chunk, 256-t half).
// Wave (ws = wave&3, th = wave>>2): h cols [hc*64+ws*16,+16), t-sub th within
// each 32-t LDS chunk. x staged cooperatively into padded LDS (stride 68:
// stage-writes and A-frag b128 reads both hit every bank exactly 8x = optimal).
// hh GEMV inlined (removes a kernel). Latency hiding from 32 waves/CU, not ILP:
// rounds 2/3/5 showed per-thread state >64 VGPR just spills (~30-560 MB scratch).
__global__ __launch_bounds__(512, 2) void fused_lstm(
    const float* __restrict__ x, const float* __restrict__ h0,
    const float* __restrict__ c0, const float* __restrict__ Wih,
    const float* __restrict__ Whh, const float* __restrict__ bih,
    const float* __restrict__ bhh, const int* __restrict__ longp,
    float* __restrict__ sbuf)
{
  const int b    = blockIdx.x;
  const int hc   = blockIdx.y;          // 0..3
  const int z    = blockIdx.z;          // 0..1
  const int tid  = threadIdx.x;
  const int wave = tid >> 6;            // 0..7
  const int lane = tid & 63;
  const int col  = lane & 15;           // A-row (t) AND B-col (h) index bits
  const int kg   = lane >> 4;           // 0..3
  const int ws   = wave & 3;            // h-slice
  const int th   = wave >> 2;           // t-sub (0..1)
  const int h    = hc * 64 + ws * 16 + col;

  __shared__ float h0s[HDIM];
  __shared__ float hh_s[256];           // [g*64 + h_local]
  __shared__ float xt[2][CH * LDR];     // double-buffered padded x tile

  const float* xb = x + (size_t)b * (TDIM * DDIM);
  const float* xz = xb + (size_t)z * ZT * DDIM;
  const float inv_long = 1.0f / (float)(*longp);

  if (tid < HDIM) h0s[tid] = h0[b * HDIM + tid];
  __syncthreads();

  // ---- inline hh: 2 threads per gate-col, 128 MACs each, 2-acc ILP ----
  {
    const int col2 = tid >> 1;          // 0..255
    const int part = tid & 1;
    const int g  = col2 >> 6;
    const int hl = col2 & 63;
    const int colw = g * HDIM + hc * 64 + hl;
    const float4* wr = (const float4*)(Whh + (size_t)colw * HDIM) + part * 32;
    const float4* hv = (const float4*)h0s + part * 32;
    float acc0 = 0.f, acc1 = 0.f;
    #pragma unroll 8
    for (int k = 0; k < 32; k += 2) {
      float4 w0 = wr[k],     h4a = hv[k];
      float4 w1 = wr[k + 1], h4b = hv[k + 1];
      acc0 += w0.x * h4a.x + w0.y * h4a.y + w0.z * h4a.z + w0.w * h4a.w;
      acc1 += w1.x * h4b.x + w1.y * h4b.y + w1.z * h4b.z + w1.w * h4b.w;
    }
    float acc = acc0 + acc1;
    acc += __shfl_xor(acc, 1, 64);
    if (part == 0) hh_s[col2] = acc + bih[colw] + bhh[colw];
  }

  // ---- W_ih fragments (B operand): contiguous 8-float read per lane ----
  s16x8 wf[4][2];
  #pragma unroll
  for (int g = 0; g < 4; ++g) {
    const float4* wrow = (const float4*)(Wih + (size_t)(g * HDIM + h) * DDIM);
    #pragma unroll
    for (int ks = 0; ks < 2; ++ks)
      wf[g][ks] = pack_bf8(wrow[kg * 2 + ks * 8], wrow[kg * 2 + ks * 8 + 1]);
  }
  const float cprev = c0[b * HDIM + h];

  // ---- stage chunk 0 (contiguous global -> padded LDS) ----
  {
    float4 v = *(const float4*)(xz + tid * 4);
    const int r = tid >> 4, c = tid & 15;
    *(float4*)&xt[0][r * LDR + c * 4] = v;
  }
  __syncthreads();

  float hhv[4];
  #pragma unroll
  for (int g = 0; g < 4; ++g) hhv[g] = hh_s[g * 64 + ws * 16 + col];

  float s0h = 0.f, s1h = 0.f, s0c = 0.f, s1c = 0.f;

  for (int ch = 0; ch < NCH; ++ch) {
    const int cur = ch & 1;
    float4 nv;
    const bool has_next = (ch + 1) < NCH;
    if (has_next)
      nv = *(const float4*)(xz + (size_t)(ch + 1) * CH * DDIM + tid * 4);

    const float* xl = &xt[cur][0];
    const int arow = (th * 16 + col) * LDR + kg * 8;
    float4 q0 = *(const float4*)(xl + arow);
    float4 q1 = *(const float4*)(xl + arow + 4);
    float4 q2 = *(const float4*)(xl + arow + 32);
    float4 q3 = *(const float4*)(xl + arow + 36);
    s16x8 a0 = pack_bf8(q0, q1);
    s16x8 a1 = pack_bf8(q2, q3);

    f32x4 acc[4];
    #pragma unroll
    for (int g = 0; g < 4; ++g) {
      f32x4 zc = {hhv[g], hhv[g], hhv[g], hhv[g]};  // bias+hh folded into C
      zc = __builtin_amdgcn_mfma_f32_16x16x32_bf16(a0, wf[g][0], zc, 0, 0, 0);
      zc = __builtin_amdgcn_mfma_f32_16x16x32_bf16(a1, wf[g][1], zc, 0, 0, 0);
      acc[g] = zc;
    }

    #pragma unroll
    for (int r = 0; r < 4; ++r) {
      const int lt = th * 16 + kg * 4 + r;          // local t in chunk
      const int tt = z * ZT + ch * CH + lt;
      float ig = sigm(acc[0][r]);
      float fg = sigm(acc[1][r]);
      float gg = tanh_fast(acc[2][r]);
      float og = sigm(acc[3][r]);
      float cc = fg * cprev + ig * gg;
      float hv = og * tanh_fast(cc);
      float2 w01 = *(const float2*)(xl + lt * LDR); // x[t][0..1] broadcast read
      float a0w = w01.x * inv_long;
      float a1w = w01.y;
      if (tt == 0) { a0w = 0.f; a1w = 0.f; }        // t=0 mask
      s0h += hv * a0w; s1h += hv * a1w;
      s0c += cc * a0w; s1c += cc * a1w;
    }

    if (has_next) {
      const int r2 = tid >> 4, c2 = tid & 15;
      *(float4*)&xt[cur ^ 1][r2 * LDR + c2 * 4] = nv;
    }
    __syncthreads();
  }

  // reduce over the 4 k-groups (lanes sharing col)
  s0h += __shfl_xor(s0h, 16, 64); s0h += __shfl_xor(s0h, 32, 64);
  s1h += __shfl_xor(s1h, 16, 64); s1h += __shfl_xor(s1h, 32, 64);
  s0c += __shfl_xor(s0c, 16, 64); s0c += __shfl_xor(s0c, 32, 64);
  s1c += __shfl_xor(s1c, 16, 64); s1c += __shfl_xor(s1c, 32, 64);

  if (kg == 0) {
    const int plane = z * 2 + th;                   // 0..3
    const size_t idx = (size_t)b * HDIM + h;
    sbuf[((size_t)(plane * 4 + 0) * BDIM * HDIM) + idx] = s0h;
    sbuf[((size_t)(plane * 4 + 1) * BDIM * HDIM) + idx] = s1h;
    sbuf[((size_t)(plane * 4 + 2) * BDIM * HDIM) + idx] = s0c;
    sbuf[((size_t)(plane * 4 + 3) * BDIM * HDIM) + idx] = s1c;
  }
}

// Grid: 128 blocks (b), 256 threads. Sums plane partials + GEMV epilogue.
__global__ __launch_bounds__(256) void out_kernel(
    const float* __restrict__ x, const float* __restrict__ f1w,
    const float* __restrict__ f1b, const float* __restrict__ f2w,
    const float* __restrict__ f2b, const int* __restrict__ longp,
    const float* __restrict__ sbuf, float* __restrict__ out)
{
  const int b = blockIdx.x, tid = threadIdx.x;
  __shared__ float s0h[256], s1h[256], s0c[256], s1c[256];
  __shared__ float wsum[8];
  const float* xb = x + (size_t)b * (TDIM * DDIM);
  const size_t idx = (size_t)b * HDIM + tid;

  float v0 = 0.f, v1 = 0.f, v2 = 0.f, v3 = 0.f;
  #pragma unroll
  for (int pl = 0; pl < NPL; ++pl) {
    v0 += sbuf[((size_t)(pl * 4 + 0) * BDIM * HDIM) + idx];
    v1 += sbuf[((size_t)(pl * 4 + 1) * BDIM * HDIM) + idx];
    v2 += sbuf[((size_t)(pl * 4 + 2) * BDIM * HDIM) + idx];
    v3 += sbuf[((size_t)(pl * 4 + 3) * BDIM * HDIM) + idx];
  }
  s0h[tid] = v0; s1h[tid] = v1; s0c[tid] = v2; s1c[tid] = v3;

  float w0p = 0.f, w1p = 0.f;
  for (int t = tid; t < TDIM; t += 256) {
    w0p += xb[t * DDIM];
    w1p += xb[t * DDIM + 1];
  }
  #pragma unroll
  for (int off = 1; off < 64; off <<= 1) {
    w0p += __shfl_xor(w0p, off, 64);
    w1p += __shfl_xor(w1p, off, 64);
  }
  if ((tid & 63) == 0) { wsum[tid >> 6] = w0p; wsum[4 + (tid >> 6)] = w1p; }
  __syncthreads();

  const float inv_long = 1.0f / (float)(*longp);
  const float W0 = (wsum[0] + wsum[1] + wsum[2] + wsum[3]) * inv_long; // all t
  const float W1 = (wsum[4] + wsum[5] + wsum[6] + wsum[7]);

  float rh, rc;
  if (tid < 128) {                       // "first": f1_w with w0-weighted sums
    const float4* wr = (const float4*)(f1w + (size_t)tid * HDIM);
    float ah = 0.f, ac = 0.f;
    #pragma unroll 8
    for (int k = 0; k < HDIM / 4; ++k) {
      float4 w = wr[k];
      ah += w.x * s0h[4*k] + w.y * s0h[4*k+1] + w.z * s0h[4*k+2] + w.w * s0h[4*k+3];
      ac += w.x * s0c[4*k] + w.y * s0c[4*k+1] + w.z * s0c[4*k+2] + w.w * s0c[4*k+3];
    }
    const float bb = f1b[tid];
    rh = ah + bb * W0;
    rc = ac + bb * W0;
  } else {                               // "second": f2_w with w1-weighted sums
    const int k0 = tid - 128;
    const float4* wr = (const float4*)(f2w + (size_t)k0 * HDIM);
    float ah = 0.f, ac = 0.f;
    #pragma unroll 8
    for (int k = 0; k < HDIM / 4; ++k) {
      float4 w = wr[k];
      ah += w.x * s1h[4*k] + w.y * s1h[4*k+1] + w.z * s1h[4*k+2] + w.w * s1h[4*k+3];
      ac += w.x * s1c[4*k] + w.y * s1c[4*k+1] + w.z * s1c[4*k+2] + w.w * s1c[4*k+3];
    }
    const float bb = f2b[k0];
    rh = ah + bb * W1;
    rc = ac + bb * W1;
  }
  out[b * HDIM + tid] = rh;                      // agg(h_all) -> (1,B,256)
  out[BDIM * HDIM + b * HDIM + tid] = rc;        // agg(c_all)
}

extern "C" void kernel_launch(void* const* d_in, const int* in_sizes, int n_in,
                              void* d_out, int out_size, void* d_ws, size_t ws_size,
                              hipStream_t stream) {
  const float* x   = (const float*)d_in[0];
  const float* h0  = (const float*)d_in[1];
  const float* c0  = (const float*)d_in[2];
  const float* Wih = (const float*)d_in[3];
  const float* Whh = (const float*)d_in[4];
  const float* bih = (const float*)d_in[5];
  const float* bhh = (const float*)d_in[6];
  const float* f1w = (const float*)d_in[7];
  const float* f1b = (const float*)d_in[8];
  const float* f2w = (const float*)d_in[9];
  const float* f2b = (const float*)d_in[10];
  const int*  longp = (const int*)d_in[11];
  float* out  = (float*)d_out;
  float* sbuf = (float*)d_ws;   // 4 planes x 4 quantities x B x H = 2 MB

  dim3 g1(BDIM, 4, 2);
  fused_lstm<<<g1, 512, 0, stream>>>(x, h0, c0, Wih, Whh, bih, bhh, longp, sbuf);
  out_kernel<<<BDIM, 256, 0, stream>>>(x, f1w, f1b, f2w, f2b, longp, sbuf, out);
}